// Round 6
// baseline (2941.104 us; speedup 1.0000x reference)
//
#include <hip/hip_runtime.h>
#include <hip/hip_bf16.h>
#include <cmath>
#include <cstdint>

// ---------------------------------------------------------------------------
// CapsuleNet forward. Round 6:
//   - prim: 64x64 tiles, DOUBLE-BUFFERED global_load_lds staging with
//     dma(s+1)-before-compute(s) ordering (latency hidden behind compute),
//     2 blocks/CU (64 KB LDS), 4 independent MFMA accumulator chains
//     (even/odd h x {hh, cross}), split-K x4 + atomicAdd epilogue.
//   - conv1: r5 structure + pass-interleaved MFMA issue.
// value = hi + lo*2^-11 (f16, lo pre-scaled 2^11); C = acc_hh + 2^-11*acc_x.
// ---------------------------------------------------------------------------

typedef _Float16 f16;
typedef _Float16 f16x8 __attribute__((ext_vector_type(8)));
typedef float    f32x4 __attribute__((ext_vector_type(4)));
typedef float    f32x16 __attribute__((ext_vector_type(16)));

__device__ __forceinline__ void dma16(const f16* g, f16* l)
{
    __builtin_amdgcn_global_load_lds(
        (const __attribute__((address_space(1))) void*)g,
        (__attribute__((address_space(3))) void*)l, 16, 0, 0);
}

// ------------------------- conv1 weight split: [n][k], k = c*81+khw ---------
__global__ void __launch_bounds__(256) w1split(
    const float* __restrict__ w, f16* __restrict__ wh, f16* __restrict__ wl)
{
    int idx = blockIdx.x * 256 + threadIdx.x;       // 65536
    int n = idx >> 8, k = idx & 255;
    float v = (k < 243) ? w[n * 243 + k] : 0.f;
    f16 hi = (f16)v;
    wh[idx] = hi;
    wl[idx] = (f16)((v - (float)hi) * 2048.0f);
}

// ------------------------- prim weight: permute + fp16 split ----------------
// in : w[n][c*81+khw]  -> out: whT/wlT [n][khw*256+c]  (vectorized 16B stores)
__global__ void __launch_bounds__(256) transpose_split_w(
    const float* __restrict__ w, f16* __restrict__ whT, f16* __restrict__ wlT)
{
    __shared__ float tile[5184];                  // 64 c x 81 khw
    const int n  = blockIdx.x;                    // 0..255
    const int cq = blockIdx.y;                    // 0..3
    const int t  = threadIdx.x;
    const float* wr = w + (size_t)n * 20736 + cq * 5184;
    for (int i = t; i < 5184; i += 256) tile[i] = wr[i];
    __syncthreads();
    f16* oh = whT + (size_t)n * 20736 + cq * 64;
    f16* ol = wlT + (size_t)n * 20736 + cq * 64;
    for (int idx = t; idx < 648; idx += 256) {    // 81 khw x 8 c-groups
        int khw = idx >> 3, cg = idx & 7;
        f16x8 vh, vl;
#pragma unroll
        for (int e = 0; e < 8; ++e) {
            float v = tile[(cg * 8 + e) * 81 + khw];
            f16 hi  = (f16)v;
            vh[e] = hi;
            vl[e] = (f16)((v - (float)hi) * 2048.0f);
        }
        *(f16x8*)&oh[khw * 256 + cg * 8] = vh;
        *(f16x8*)&ol[khw * 256 + cg * 8] = vl;
    }
}

// ------------------------- conv1: fused im2col + fp16-split MFMA ------------
// C[M=chunk*400, 256] = im2col(x)[M,256] * W1[256,256]; bias+ReLU; hh/hl NHWC.
__global__ void __launch_bounds__(256) conv1_mfma(
    const float* __restrict__ x,
    const f16* __restrict__ wh, const f16* __restrict__ wl,
    const float* __restrict__ bias, f16* __restrict__ hh, f16* __restrict__ hl)
{
    __shared__ __align__(16) f16 Ah[4096], Al[4096], Bh[4096], Bl[4096];
    __shared__ int otab[256];
    const int t  = threadIdx.x;
    const int m0 = blockIdx.x * 64;
    const int n0 = blockIdx.y * 64;

    {   // otab: k -> x offset (c*784 + ky*28 + kx), -1 pads
        int k = t;
        int off = -1;
        if (k < 243) {
            int c = k / 81, khw = k - c * 81;
            int ky = khw / 9, kx = khw - ky * 9;
            off = c * 784 + ky * 28 + kx;
        }
        otab[t] = off;
    }

    const int sr = t >> 3;
    const int sg = t & 7;
    const float* xb[2];
    int bbase[2], wofs[2];
#pragma unroll
    for (int pp = 0; pp < 2; ++pp) {
        int r = pp * 32 + sr;
        int m = m0 + r;
        int bb = m / 400, pix = m - bb * 400;
        int py = pix / 20, px = pix - py * 20;
        xb[pp] = x + (size_t)bb * 2352 + py * 28 + px;
        bbase[pp] = (n0 + r) * 256 + sg * 8;
        wofs[pp] = r * 64 + ((sg ^ (r & 7)) * 8);
    }

    float rx[2][8];
    f16x8 rBh[2], rBl[2];
    __syncthreads();                              // otab ready
    auto stage = [&](int s) {
#pragma unroll
        for (int pp = 0; pp < 2; ++pp) {
#pragma unroll
            for (int e = 0; e < 8; ++e) {
                int off = otab[s * 64 + sg * 8 + e];
                rx[pp][e] = (off >= 0) ? xb[pp][off] : 0.f;
            }
            rBh[pp] = *(const f16x8*)&wh[bbase[pp] + s * 64];
            rBl[pp] = *(const f16x8*)&wl[bbase[pp] + s * 64];
        }
    };

    const int lane = t & 63;
    const int wv   = t >> 6;
    const int wm   = wv >> 1, wn = wv & 1;
    const int li   = lane & 15, lq = lane >> 4;

    f32x4 acc_h[2][2], acc_x[2][2];
#pragma unroll
    for (int i = 0; i < 2; ++i)
#pragma unroll
        for (int j = 0; j < 2; ++j) {
            acc_h[i][j] = (f32x4){0.f, 0.f, 0.f, 0.f};
            acc_x[i][j] = (f32x4){0.f, 0.f, 0.f, 0.f};
        }

    stage(0);

    for (int s = 0; s < 4; ++s) {
        __syncthreads();
#pragma unroll
        for (int pp = 0; pp < 2; ++pp) {
            f16x8 vh, vl;
#pragma unroll
            for (int e = 0; e < 8; ++e) {
                float v = rx[pp][e];
                f16 hi = (f16)v;
                vh[e] = hi;
                vl[e] = (f16)((v - (float)hi) * 2048.0f);
            }
            *(f16x8*)&Ah[wofs[pp]] = vh;
            *(f16x8*)&Al[wofs[pp]] = vl;
            *(f16x8*)&Bh[wofs[pp]] = rBh[pp];
            *(f16x8*)&Bl[wofs[pp]] = rBl[pp];
        }
        __syncthreads();
        if (s + 1 < 4) stage(s + 1);
#pragma unroll
        for (int h = 0; h < 2; ++h) {
            int g = h * 4 + lq;
            f16x8 ah[2], al[2], bh[2], bl[2];
#pragma unroll
            for (int mf = 0; mf < 2; ++mf) {
                int r = wm * 32 + mf * 16 + li;
                int u = r * 64 + ((g ^ (r & 7)) * 8);
                ah[mf] = *(const f16x8*)&Ah[u];
                al[mf] = *(const f16x8*)&Al[u];
            }
#pragma unroll
            for (int nf = 0; nf < 2; ++nf) {
                int r = wn * 32 + nf * 16 + li;
                int u = r * 64 + ((g ^ (r & 7)) * 8);
                bh[nf] = *(const f16x8*)&Bh[u];
                bl[nf] = *(const f16x8*)&Bl[u];
            }
            // pass-interleaved issue: 3 loops of 4 independent MFMAs
#pragma unroll
            for (int mf = 0; mf < 2; ++mf)
#pragma unroll
                for (int nf = 0; nf < 2; ++nf)
                    acc_h[mf][nf] = __builtin_amdgcn_mfma_f32_16x16x32_f16(
                        ah[mf], bh[nf], acc_h[mf][nf], 0, 0, 0);
#pragma unroll
            for (int mf = 0; mf < 2; ++mf)
#pragma unroll
                for (int nf = 0; nf < 2; ++nf)
                    acc_x[mf][nf] = __builtin_amdgcn_mfma_f32_16x16x32_f16(
                        ah[mf], bl[nf], acc_x[mf][nf], 0, 0, 0);
#pragma unroll
            for (int mf = 0; mf < 2; ++mf)
#pragma unroll
                for (int nf = 0; nf < 2; ++nf)
                    acc_x[mf][nf] = __builtin_amdgcn_mfma_f32_16x16x32_f16(
                        al[mf], bh[nf], acc_x[mf][nf], 0, 0, 0);
        }
    }

    float bn[2];
    bn[0] = bias[n0 + wn * 32 + li];
    bn[1] = bias[n0 + wn * 32 + 16 + li];
#pragma unroll
    for (int mf = 0; mf < 2; ++mf) {
        int mb = m0 + wm * 32 + mf * 16 + lq * 4;
#pragma unroll
        for (int r = 0; r < 4; ++r) {
            size_t row = (size_t)(mb + r) * 256;
#pragma unroll
            for (int nf = 0; nf < 2; ++nf) {
                int n   = n0 + wn * 32 + nf * 16 + li;
                float v = acc_h[mf][nf][r]
                        + acc_x[mf][nf][r] * (1.0f / 2048.0f) + bn[nf];
                v = fmaxf(v, 0.f);
                f16 hi = (f16)v;
                hh[row + n] = hi;
                hl[row + n] = (f16)((v - (float)hi) * 2048.0f);
            }
        }
    }
}

// ------------------------- prim conv: 64x64 dbuf-DMA 32x32x16 MFMA ----------
// GEMM: C[M=chunk*36, 256] += im2col(h)[M, Kq] * W[Kq, 256], Kq = 81*64 (kz).
// Block 64x64, 4 waves 2x2 (32x32 each). Double-buffered LDS (64 KB total):
//   for s: sync; dma(s+1 -> other buf); compute(cur)  -> DMA hidden by compute.
// LDS XOR swizzle row*64 + ((g^(r&7))*8); DMA lane map: lane l=(dj*8+dq)
// loads (row R+dj, group dq^dj) -> uniform base + l*16 == swizzled slot.
__global__ void __launch_bounds__(256) prim_mfma32(
    const f16* __restrict__ hh, const f16* __restrict__ hl,
    const f16* __restrict__ whT, const f16* __restrict__ wlT,
    const float* __restrict__ bias, float* __restrict__ p, int b_base)
{
    __shared__ __align__(16) f16 Ah[2][4096], Al[2][4096], Bh[2][4096], Bl[2][4096];
    const int t    = threadIdx.x;
    const int m0   = blockIdx.x * 64;
    const int n0   = blockIdx.y * 64;
    const int kz64 = blockIdx.z * 64;

    const int l  = t & 63, wv = t >> 6;
    const int wm = wv >> 1, wn = wv & 1;
    const int lr = l & 31, lh = l >> 5;

    // DMA coords: wave wv stages rows wv*16 + i*8 + dj (i<2) of all 4 tiles
    const int dj = l >> 3, dq = l & 7, dg = dq ^ dj;
    int aoff[2], boff[2];
#pragma unroll
    for (int i = 0; i < 2; ++i) {
        int r  = wv * 16 + i * 8 + dj;
        int m  = m0 + r;
        int bb = m / 36, pix = m - bb * 36;
        int py = pix / 6, px = pix - py * 6;
        aoff[i] = (bb * 400 + py * 40 + px * 2) * 256 + kz64 + dg * 8;
        boff[i] = (n0 + r) * 20736 + kz64 + dg * 8;
    }

    auto dma_step = [&](int s, int nb) {
        int ky = s / 9, kx = s - ky * 9;
        int aAdd = (ky * 20 + kx) * 256;
        int bAdd = s * 256;
#pragma unroll
        for (int i = 0; i < 2; ++i) {
            int lb = (wv * 16 + i * 8) * 64;      // wave-uniform LDS base
            dma16(hh  + aoff[i] + aAdd, &Ah[nb][lb]);
            dma16(hl  + aoff[i] + aAdd, &Al[nb][lb]);
            dma16(whT + boff[i] + bAdd, &Bh[nb][lb]);
            dma16(wlT + boff[i] + bAdd, &Bl[nb][lb]);
        }
    };

    // 4 independent accumulator chains: even/odd h-pair x {hh, cross}
    f32x16 acc_h0, acc_h1, acc_x0, acc_x1;
#pragma unroll
    for (int e = 0; e < 16; ++e) {
        acc_h0[e] = 0.f; acc_h1[e] = 0.f; acc_x0[e] = 0.f; acc_x1[e] = 0.f;
    }

    dma_step(0, 0);

    for (int s = 0; s < 81; ++s) {
        const int cur = s & 1;
        __syncthreads();                          // drains dma for buf[cur]
        if (s + 1 < 81) dma_step(s + 1, cur ^ 1); // in flight during compute
        const f16* AhB = &Ah[cur][0];
        const f16* AlB = &Al[cur][0];
        const f16* BhB = &Bh[cur][0];
        const f16* BlB = &Bl[cur][0];
#pragma unroll
        for (int hp = 0; hp < 2; ++hp) {          // h-pairs {0,1}, {2,3}
            f16x8 ah[2], al[2], bh[2], bl[2];
#pragma unroll
            for (int e = 0; e < 2; ++e) {
                int gg = (hp * 2 + e) * 2 + lh;
                int ra = wm * 32 + lr;
                int ua = ra * 64 + ((gg ^ (ra & 7)) * 8);
                ah[e] = *(const f16x8*)&AhB[ua];
                al[e] = *(const f16x8*)&AlB[ua];
                int rb = wn * 32 + lr;
                int ub = rb * 64 + ((gg ^ (rb & 7)) * 8);
                bh[e] = *(const f16x8*)&BhB[ub];
                bl[e] = *(const f16x8*)&BlB[ub];
            }
            acc_h0 = __builtin_amdgcn_mfma_f32_32x32x16_f16(ah[0], bh[0], acc_h0, 0, 0, 0);
            acc_h1 = __builtin_amdgcn_mfma_f32_32x32x16_f16(ah[1], bh[1], acc_h1, 0, 0, 0);
            acc_x0 = __builtin_amdgcn_mfma_f32_32x32x16_f16(ah[0], bl[0], acc_x0, 0, 0, 0);
            acc_x1 = __builtin_amdgcn_mfma_f32_32x32x16_f16(ah[1], bl[1], acc_x1, 0, 0, 0);
            acc_x0 = __builtin_amdgcn_mfma_f32_32x32x16_f16(al[0], bh[0], acc_x0, 0, 0, 0);
            acc_x1 = __builtin_amdgcn_mfma_f32_32x32x16_f16(al[1], bh[1], acc_x1, 0, 0, 0);
        }
    }

    // epilogue: C/D 32x32 layout: col = lane&31, row = (reg&3)+8*(reg>>2)+4*lh
    float bn = (kz64 == 0) ? bias[n0 + wn * 32 + lr] : 0.f;
    int   n   = n0 + wn * 32 + lr;
    int   cap = n >> 3, vec = n & 7;
#pragma unroll
    for (int reg = 0; reg < 16; ++reg) {
        int row = (reg & 3) + 8 * (reg >> 2) + 4 * lh;
        int m   = m0 + wm * 32 + row;
        int bb  = m / 36, pix = m - bb * 36;
        size_t rowp = (size_t)(b_base + bb) * 9216 + pix * 8;
        float v = (acc_h0[reg] + acc_h1[reg])
                + (acc_x0[reg] + acc_x1[reg]) * (1.0f / 2048.0f) + bn;
        atomicAdd(&p[rowp + cap * 288 + vec], v);
    }
}

// ------------------------- dynamic routing (register-priors) ----------------
__global__ void __launch_bounds__(384) routing2(
    const float* __restrict__ p, const float* __restrict__ rw,
    float* __restrict__ caps)
{
    const int b = blockIdx.x;
    const int c = blockIdx.y;
    const int t = threadIdx.x;
    const int lane = t & 63, wid = t >> 6;
    __shared__ float redbuf[6];
    __shared__ float tred[6][16];
    __shared__ float outv[16];

    const float* pb  = p  + (size_t)b * 9216;
    const float* rwc = rw + (size_t)c * 147456;

    float q[3][16];
    float l[3] = {0.f, 0.f, 0.f};

#pragma unroll
    for (int j = 0; j < 3; ++j) {
        int r = t + 384 * j;
        float4 p0 = *(const float4*)&pb[r * 8];
        float4 p1 = *(const float4*)&pb[r * 8 + 4];
        float pr[8] = {p0.x, p0.y, p0.z, p0.w, p1.x, p1.y, p1.z, p1.w};
#pragma unroll
        for (int v = 0; v < 16; ++v) q[j][v] = 0.f;
        const float* wr = rwc + (size_t)r * 128;
#pragma unroll
        for (int i = 0; i < 8; ++i) {
#pragma unroll
            for (int v4 = 0; v4 < 4; ++v4) {
                float4 w4 = *(const float4*)&wr[i * 16 + v4 * 4];
                q[j][v4 * 4 + 0] = fmaf(pr[i], w4.x, q[j][v4 * 4 + 0]);
                q[j][v4 * 4 + 1] = fmaf(pr[i], w4.y, q[j][v4 * 4 + 1]);
                q[j][v4 * 4 + 2] = fmaf(pr[i], w4.z, q[j][v4 * 4 + 2]);
                q[j][v4 * 4 + 3] = fmaf(pr[i], w4.w, q[j][v4 * 4 + 3]);
            }
        }
    }

    for (int it = 0; it < 3; ++it) {
        float lm = fmaxf(fmaxf(l[0], l[1]), l[2]);
#pragma unroll
        for (int off = 32; off; off >>= 1) lm = fmaxf(lm, __shfl_down(lm, off, 64));
        __syncthreads();
        if (lane == 0) redbuf[wid] = lm;
        __syncthreads();
        lm = fmaxf(fmaxf(fmaxf(redbuf[0], redbuf[1]), fmaxf(redbuf[2], redbuf[3])),
                   fmaxf(redbuf[4], redbuf[5]));

        float e[3];
        float ls = 0.f;
#pragma unroll
        for (int j = 0; j < 3; ++j) { e[j] = __expf(l[j] - lm); ls += e[j]; }
#pragma unroll
        for (int off = 32; off; off >>= 1) ls += __shfl_down(ls, off, 64);
        __syncthreads();
        if (lane == 0) redbuf[wid] = ls;
        __syncthreads();
        ls = redbuf[0] + redbuf[1] + redbuf[2] + redbuf[3] + redbuf[4] + redbuf[5];
        const float inv = 1.f / ls;

        float tv[16];
#pragma unroll
        for (int v = 0; v < 16; ++v)
            tv[v] = fmaf(e[0], q[0][v], fmaf(e[1], q[1][v], e[2] * q[2][v]));
#pragma unroll
        for (int v = 0; v < 16; ++v) {
            float xv = tv[v];
#pragma unroll
            for (int off = 32; off; off >>= 1) xv += __shfl_down(xv, off, 64);
            tv[v] = xv;
        }
        __syncthreads();
        if (lane == 0) {
#pragma unroll
            for (int v = 0; v < 16; ++v) tred[wid][v] = tv[v];
        }
        __syncthreads();
        if (t < 16)
            outv[t] = (tred[0][t] + tred[1][t] + tred[2][t]
                     + tred[3][t] + tred[4][t] + tred[5][t]) * inv;
        __syncthreads();

        float s2 = 0.f;
#pragma unroll
        for (int v = 0; v < 16; ++v) s2 += outv[v] * outv[v];
        const float scale = s2 / ((1.f + s2) * sqrtf(s2));

        if (it == 2) {
            if (t < 16) caps[((size_t)b * 2 + c) * 16 + t] = scale * outv[t];
        } else {
            float ov[16];
#pragma unroll
            for (int v = 0; v < 16; ++v) ov[v] = scale * outv[v];
#pragma unroll
            for (int j = 0; j < 3; ++j) {
                float d = 0.f;
#pragma unroll
                for (int v = 0; v < 16; ++v) d = fmaf(q[j][v], ov[v], d);
                l[j] += d;
            }
        }
    }
}

// ------------------------- class softmax + argmax mask ----------------------
__global__ void __launch_bounds__(256) mask_kernel(
    const float* __restrict__ caps, float* __restrict__ cls_out,
    float* __restrict__ masked)
{
    int b = blockIdx.x * 256 + threadIdx.x;
    if (b < 1024) {
        const float* cb = caps + (size_t)b * 32;
        float n0 = 0.f, n1 = 0.f;
#pragma unroll
        for (int v = 0; v < 16; ++v) {
            n0 = fmaf(cb[v], cb[v], n0);
            n1 = fmaf(cb[16 + v], cb[16 + v], n1);
        }
        n0 = sqrtf(n0); n1 = sqrtf(n1);
        float mx = fmaxf(n0, n1);
        float e0 = expf(n0 - mx), e1 = expf(n1 - mx);
        float inv = 1.f / (e0 + e1);
        cls_out[b * 2 + 0] = e0 * inv;
        cls_out[b * 2 + 1] = e1 * inv;
        int cs = (n1 > n0) ? 1 : 0;
#pragma unroll
        for (int v = 0; v < 16; ++v) {
            masked[(size_t)b * 32 + v]      = (cs == 0) ? cb[v] : 0.f;
            masked[(size_t)b * 32 + 16 + v] = (cs == 1) ? cb[16 + v] : 0.f;
        }
    }
}

// ------------------------- decoder GEMM -------------------------------------
template<int ACT>
__global__ void __launch_bounds__(256) dense_gemm(
    const float* __restrict__ A, const float* __restrict__ Bw,
    const float* __restrict__ bias, float* __restrict__ out,
    int M, int N, int K)
{
    __shared__ __align__(16) float As[16][128];
    __shared__ __align__(16) float Bs[16][64];
    const int t  = threadIdx.x;
    const int m0 = blockIdx.x * 128, n0 = blockIdx.y * 64;
    const int tx = t & 15, ty = t >> 4;
    const int am = t >> 1;
    const int ak = (t & 1) * 8;
    const int nb = (t & 15) * 4, kb = t >> 4;

    float acc[8][4];
#pragma unroll
    for (int i = 0; i < 8; ++i)
#pragma unroll
        for (int j = 0; j < 4; ++j) acc[i][j] = 0.f;

    for (int k0i = 0; k0i < K; k0i += 16) {
        {
            const float* ap = A + (size_t)(m0 + am) * K + k0i + ak;
            float4 v0 = *(const float4*)ap;
            float4 v1 = *(const float4*)(ap + 4);
            As[ak + 0][am] = v0.x; As[ak + 1][am] = v0.y;
            As[ak + 2][am] = v0.z; As[ak + 3][am] = v0.w;
            As[ak + 4][am] = v1.x; As[ak + 5][am] = v1.y;
            As[ak + 6][am] = v1.z; As[ak + 7][am] = v1.w;
        }
        {
            int k = k0i + kb;
            int n = n0 + nb;
            float4 v4 = make_float4(0.f, 0.f, 0.f, 0.f);
            if (n + 3 < N) {
                v4 = *(const float4*)&Bw[(size_t)k * N + n];
            } else {
                float tmp[4] = {0.f, 0.f, 0.f, 0.f};
#pragma unroll
                for (int e = 0; e < 4; ++e)
                    if (n + e < N) tmp[e] = Bw[(size_t)k * N + n + e];
                v4 = make_float4(tmp[0], tmp[1], tmp[2], tmp[3]);
            }
            *(float4*)&Bs[kb][nb] = v4;
        }
        __syncthreads();
#pragma unroll
        for (int kk = 0; kk < 16; ++kk) {
            float4 a0 = *(const float4*)&As[kk][ty * 8];
            float4 a1 = *(const float4*)&As[kk][ty * 8 + 4];
            float4 b0 = *(const float4*)&Bs[kk][tx * 4];
            float av[8] = {a0.x, a0.y, a0.z, a0.w, a1.x, a1.y, a1.z, a1.w};
            float bv[4] = {b0.x, b0.y, b0.z, b0.w};
#pragma unroll
            for (int i = 0; i < 8; ++i)
#pragma unroll
                for (int j = 0; j < 4; ++j)
                    acc[i][j] = fmaf(av[i], bv[j], acc[i][j]);
        }
        __syncthreads();
    }
#pragma unroll
    for (int i = 0; i < 8; ++i) {
        int mm = m0 + ty * 8 + i;
#pragma unroll
        for (int j = 0; j < 4; ++j) {
            int n = n0 + tx * 4 + j;
            if (n < N) {
                float v = acc[i][j] + bias[n];
                v = (ACT == 0) ? fmaxf(v, 0.f) : 1.f / (1.f + expf(-v));
                out[(size_t)mm * N + n] = v;
            }
        }
    }
}

// ------------------------- host launcher ------------------------------------
extern "C" void kernel_launch(void* const* d_in, const int* in_sizes, int n_in,
                              void* d_out, int out_size, void* d_ws, size_t ws_size,
                              hipStream_t stream)
{
    const float* x       = (const float*)d_in[0];
    const float* conv1_w = (const float*)d_in[1];
    const float* conv1_b = (const float*)d_in[2];
    const float* prim_w  = (const float*)d_in[3];
    const float* prim_b  = (const float*)d_in[4];
    const float* route_w = (const float*)d_in[5];
    const float* dec_w1  = (const float*)d_in[6];
    const float* dec_b1  = (const float*)d_in[7];
    const float* dec_w2  = (const float*)d_in[8];
    const float* dec_b2  = (const float*)d_in[9];
    const float* dec_w3  = (const float*)d_in[10];
    const float* dec_b3  = (const float*)d_in[11];

    f16*   whT1 = (f16*)d_ws;                       //   65536 halves
    f16*   wlT1 = whT1 + 65536;
    f16*   whT  = wlT1 + 65536;                     // 5308416 halves
    f16*   wlT  = whT + 5308416;
    float* pbuf   = (float*)(wlT + 5308416);        // 9437184 f32
    float* caps   = pbuf + 9437184;
    float* masked = caps + 32768;
    float* d1     = masked + 32768;
    float* d2     = d1 + 524288;
    f16*   hbase  = (f16*)(d2 + 1048576);
    float* outF   = (float*)d_out;

    const size_t fixed_bytes = 65798144ull;
    int chunk = 64;
    const int cand[4] = {512, 256, 128, 64};
    for (int i = 0; i < 4; ++i) {
        if (fixed_bytes + (size_t)cand[i] * 409600ull <= ws_size) {
            chunk = cand[i];
            break;
        }
    }
    f16* hh = hbase;
    f16* hl = hh + (size_t)chunk * 102400;

    // p accumulated via atomics (split-K) -> zero it
    hipMemsetAsync(pbuf, 0, 9437184ull * sizeof(float), stream);

    w1split<<<256, 256, 0, stream>>>(conv1_w, whT1, wlT1);
    transpose_split_w<<<dim3(256, 4), 256, 0, stream>>>(prim_w, whT, wlT);

    const int nchunks = 1024 / chunk;
    for (int ci = 0; ci < nchunks; ++ci) {
        const float* xin = x + (size_t)ci * chunk * 2352;
        conv1_mfma<<<dim3(chunk * 400 / 64, 4), 256, 0, stream>>>(
            xin, whT1, wlT1, conv1_b, hh, hl);
        prim_mfma32<<<dim3(chunk * 36 / 64, 4, 4), 256, 0, stream>>>(
            hh, hl, whT, wlT, prim_b, pbuf, ci * chunk);
    }

    routing2<<<dim3(1024, 2), 384, 0, stream>>>(pbuf, route_w, caps);
    mask_kernel<<<4, 256, 0, stream>>>(caps, outF, masked);

    dense_gemm<0><<<dim3(8, 8),  256, 0, stream>>>(masked, dec_w1, dec_b1, d1, 1024, 512, 32);
    dense_gemm<0><<<dim3(8, 16), 256, 0, stream>>>(d1, dec_w2, dec_b2, d2, 1024, 1024, 512);
    dense_gemm<1><<<dim3(8, 13), 256, 0, stream>>>(d2, dec_w3, dec_b3, outF + 2048, 1024, 784, 1024);
}